// Round 3
// 356.986 us; speedup vs baseline: 1.0690x; 1.0690x over previous
//
#include <hip/hip_runtime.h>
#include <math.h>

#define HH   1024
#define TT   2048
#define BB   32
#define NC   32            // chunks along T  -> 32*32 = 1024 blocks (4 blocks/CU)
#define TC   (TT / NC)     // 64 timesteps per block
#define NWV  4             // waves per block
#define TPW  (TC / NWV)    // 16 timesteps per wave
#define NTH  (NWV * 64)    // 256 threads
#define KSL  16            // k-slices for compute_v partials

typedef float f4 __attribute__((ext_vector_type(4)));

// ---------------- kernel 0a: vpart[ks][h] = sum_{k in slice} W_v[k]*W_attn[k,H+h] ----
__global__ __launch_bounds__(256) void compute_v_part(
    const float* __restrict__ W_attn, const float* __restrict__ W_v,
    float* __restrict__ vpart)
{
    const int h  = blockIdx.x * 256 + threadIdx.x;   // blockIdx.x in [0,4)
    const int ks = blockIdx.y;                       // [0,KSL)
    const int k0 = ks * (HH / KSL);
    const float* col = W_attn + HH + h;
    float s = 0.f;
#pragma unroll 8
    for (int k = k0; k < k0 + HH / KSL; ++k)
        s = fmaf(W_v[k], col[(size_t)k * (2 * HH)], s);
    vpart[ks * HH + h] = s;
}

// ---------------- kernel 0b: v[h] = sum_ks vpart[ks][h] ----------------
__global__ __launch_bounds__(256) void compute_v_reduce(
    const float* __restrict__ vpart, float* __restrict__ v_out)
{
    const int h = blockIdx.x * 256 + threadIdx.x;
    float s = 0.f;
#pragma unroll
    for (int ks = 0; ks < KSL; ++ks) s += vpart[ks * HH + h];
    v_out[h] = s;
}

// ---------------- kernel 1: fused score + online softmax + weighted sum ----------
// Wave-private: each wave covers full H (lane owns 16 floats), handles TPW
// contiguous timesteps with zero barriers in the hot loop; one LDS merge at end.
// v2: depth-2 prefetch, deferred-rescale online softmax (exact; branch is
// wave-uniform since p is identical on all lanes after the butterfly),
// 4-way tree dot, nontemporal enc loads (native vector type for the builtin).
__global__ __launch_bounds__(NTH, 4) void attn_pass_kernel(
    const float* __restrict__ enc, const float* __restrict__ v,
    float* __restrict__ ws_m, float* __restrict__ ws_l,
    float* __restrict__ ws_acc)
{
    const int c    = blockIdx.x;
    const int b    = blockIdx.y;
    const int tid  = threadIdx.x;
    const int lane = tid & 63;
    const int wave = tid >> 6;

    // lane's H ownership: float4 slots lane, lane+64, lane+128, lane+192
    f4 v4[4];
#pragma unroll
    for (int j = 0; j < 4; ++j)
        v4[j] = reinterpret_cast<const f4*>(v)[lane + 64 * j];

    const int t0 = c * TC + wave * TPW;
    const f4* enc4 = reinterpret_cast<const f4*>(enc)
                     + ((size_t)b * TT + t0) * (HH / 4);

    float m = -INFINITY;
    float l = 0.f;
    f4 acc[4] = {(f4)(0.f), (f4)(0.f), (f4)(0.f), (f4)(0.f)};

    // depth-2 prefetch pipeline: e0 = tile i, e1 = tile i+1
    f4 e0[4], e1[4];
#pragma unroll
    for (int j = 0; j < 4; ++j)
        e0[j] = __builtin_nontemporal_load(enc4 + lane + 64 * j);
#pragma unroll
    for (int j = 0; j < 4; ++j)
        e1[j] = __builtin_nontemporal_load(enc4 + (HH / 4) + lane + 64 * j);

#pragma unroll
    for (int i = 0; i < TPW; ++i) {
        f4 e2[4];
        if (i + 2 < TPW) {
#pragma unroll
            for (int j = 0; j < 4; ++j)
                e2[j] = __builtin_nontemporal_load(
                    enc4 + (size_t)(i + 2) * (HH / 4) + lane + 64 * j);
        } else {
#pragma unroll
            for (int j = 0; j < 4; ++j) e2[j] = e1[j];
        }

        // dot(enc_t, v) partial on this lane — 4-way tree to shorten dep chain
        float px = 0.f, py = 0.f, pz = 0.f, pw = 0.f;
#pragma unroll
        for (int j = 0; j < 4; ++j) {
            px = fmaf(e0[j][0], v4[j][0], px);
            py = fmaf(e0[j][1], v4[j][1], py);
            pz = fmaf(e0[j][2], v4[j][2], pz);
            pw = fmaf(e0[j][3], v4[j][3], pw);
        }
        float p = (px + py) + (pz + pw);

        // butterfly all-reduce across 64 lanes -> p wave-uniform
#pragma unroll
        for (int off = 1; off < 64; off <<= 1)
            p += __shfl_xor(p, off, 64);

        // deferred-rescale online softmax (exact):
        //  p >  m: new max -> w = exp(p-p) = 1, rescale acc by alpha
        //  p <= m: max unchanged -> alpha = 1, just accumulate w*e
        // branch is wave-uniform (p, m identical on all lanes).
        if (p > m) {
            const float alpha = __expf(m - p);   // first iter: exp(-inf)=0
            l = fmaf(l, alpha, 1.f);
#pragma unroll
            for (int j = 0; j < 4; ++j)
                acc[j] = acc[j] * alpha + e0[j];
            m = p;
        } else {
            const float w = __expf(p - m);
            l += w;
#pragma unroll
            for (int j = 0; j < 4; ++j)
                acc[j] = acc[j] + e0[j] * w;
        }

        // rotate pipeline
#pragma unroll
        for (int j = 0; j < 4; ++j) { e0[j] = e1[j]; e1[j] = e2[j]; }
    }

    // ---- block-level merge of the 4 wave-private (m, l, acc) ----
    __shared__ float sm[NWV], sl[NWV];
    __shared__ f4 sacc[NWV * 256];   // 16 KB

    if (lane == 0) { sm[wave] = m; sl[wave] = l; }
    __syncthreads();

    float M = -INFINITY;
#pragma unroll
    for (int w2 = 0; w2 < NWV; ++w2) M = fmaxf(M, sm[w2]);
    const float myscale = __expf(m - M);

#pragma unroll
    for (int j = 0; j < 4; ++j)
        sacc[wave * 256 + lane + 64 * j] = acc[j] * myscale;
    __syncthreads();

    // thread tid reduces float4-slot `tid` across the 4 waves
    f4 r = (f4)(0.f);
#pragma unroll
    for (int w2 = 0; w2 < NWV; ++w2)
        r += sacc[w2 * 256 + tid];

    const int idx = b * NC + c;
    reinterpret_cast<f4*>(ws_acc + (size_t)idx * HH)[tid] = r;
    if (tid == 0) {
        float L = 0.f;
#pragma unroll
        for (int w2 = 0; w2 < NWV; ++w2) L = fmaf(sl[w2], __expf(sm[w2] - M), L);
        ws_m[idx] = M;
        ws_l[idx] = L;
    }
}

// ---------------- kernel 2: combine chunk partials ----------------
__global__ __launch_bounds__(256) void combine_kernel(
    const float* __restrict__ ws_m, const float* __restrict__ ws_l,
    const float* __restrict__ ws_acc, float* __restrict__ out)
{
    const int b   = blockIdx.x;
    const int tid = threadIdx.x;

    float M = -INFINITY;
#pragma unroll
    for (int c = 0; c < NC; ++c) M = fmaxf(M, ws_m[b * NC + c]);

    float L = 0.f;
    f4 r = (f4)(0.f);
#pragma unroll
    for (int c = 0; c < NC; ++c) {
        const float sc = __expf(ws_m[b * NC + c] - M);
        L = fmaf(sc, ws_l[b * NC + c], L);
        const f4 a =
            reinterpret_cast<const f4*>(ws_acc + (size_t)(b * NC + c) * HH)[tid];
        r += a * sc;
    }
    const float inv = 1.f / L;
    reinterpret_cast<f4*>(out + (size_t)b * HH)[tid] = r * inv;
}

extern "C" void kernel_launch(void* const* d_in, const int* in_sizes, int n_in,
                              void* d_out, int out_size, void* d_ws, size_t ws_size,
                              hipStream_t stream) {
    // inputs: 0 encoder_outputs (B,T,H) f32 | 1 hidden | 2 W_attn (H,2H) f32
    //         3 b_attn | 4 W_v (1,H) f32 | 5 b_v
    // hidden / b_attn / b_v are constant in t -> cancel under softmax.
    const float* enc    = (const float*)d_in[0];
    const float* W_attn = (const float*)d_in[2];
    const float* W_v    = (const float*)d_in[4];
    float* out = (float*)d_out;

    float* ws     = (float*)d_ws;
    float* v      = ws;                          // 1024
    float* vpart  = ws + 1024;                   // 16*1024
    float* ws_m   = ws + 1024 + KSL * HH;        // 1024
    float* ws_l   = ws_m + BB * NC;              // 1024
    float* ws_acc = ws_l + BB * NC;              // 32*32*1024 = 4 MB

    compute_v_part<<<dim3(4, KSL), 256, 0, stream>>>(W_attn, W_v, vpart);
    compute_v_reduce<<<HH / 256, 256, 0, stream>>>(vpart, v);
    attn_pass_kernel<<<dim3(NC, BB), NTH, 0, stream>>>(enc, v, ws_m, ws_l, ws_acc);
    combine_kernel<<<BB, 256, 0, stream>>>(ws_m, ws_l, ws_acc, out);
}